// Round 10
// baseline (181.193 us; speedup 1.0000x reference)
//
#include <hip/hip_runtime.h>
#include <math.h>

#define N_TOK 8192
#define DIM   1024
#define NE    8
#define NR    16
#define NO    3072
#define OUT_ELEMS (N_TOK * NO)   // 25165824

__device__ __forceinline__ float softplusf(float z) {
  return z > 0.f ? z + log1pf(expf(-z)) : log1pf(expf(z));
}
__device__ __forceinline__ float ncdf(float z) {
  return 0.5f * erfcf(-z * 0.70710678118654752f);
}

#define FMA4(A, S, W) { (A).x = fmaf((S),(W).x,(A).x); (A).y = fmaf((S),(W).y,(A).y); \
                        (A).z = fmaf((S),(W).z,(A).z); (A).w = fmaf((S),(W).w,(A).w); }
#define Z4 make_float4(0.f,0.f,0.f,0.f)

typedef __attribute__((address_space(3))) void LDSV;
typedef const __attribute__((address_space(1))) void GLBV;
__device__ __forceinline__ void stage16(const void* g, void* l) {
  __builtin_amdgcn_global_load_lds((GLBV*)g, (LDSV*)l, 16, 0, 0);
}
#define WAITVM(N) { asm volatile("s_waitcnt vmcnt(" #N ")" ::: "memory"); \
                    __builtin_amdgcn_sched_barrier(0); }
#define SBAR() { __builtin_amdgcn_s_barrier(); __builtin_amdgcn_sched_barrier(0); }

// LDS maps (dynamic): [ weights 64K | x 4 x 16K | lgS ]   pdf overlays x-buf0
#define WL_OFF  0
#define XB_OFF  65536
#define LG_OFF  (65536 + 65536)
#define KA4_SMEM (LG_OFF + 2560)
#define KD4_SMEM (65536 + 65536 + 128)   // lal | xb | toks ; pdf overlays xb0

// ---------------------------------------------------------------------------
// kA4: gating GEMV, pipelined. 256 blocks x 32 tokens, K=1024 in 8 chunks of
// 128. w[1024][16] staged once; x chunks 4-deep via global_load_lds with
// counted vmcnt (never 0 mid-loop) + raw s_barrier. Thread = (tok,og,kg):
// float4 acc (4 outs, half-K). Rotation-swizzled x slots. One-time kg-reduce
// in LDS; epilogue t<32: softplus/top-2/ncdf/ballot/partials.
// ---------------------------------------------------------------------------
__global__ __launch_bounds__(256) void kA4(const float* __restrict__ x,
    const float* __restrict__ wg, const float* __restrict__ wn,
    const float* __restrict__ nz, int* __restrict__ eid, float* __restrict__ part) {
  extern __shared__ char smem[];
  float* wl  = (float*)(smem + WL_OFF);
  float* lgS = (float*)(smem + LG_OFF);
  float* pdf = (float*)(smem + XB_OFF);       // [2][32][20] overlay (post-loop)
  int t = threadIdx.x;
  int n0 = blockIdx.x << 5;
  int tok = t & 31, q = t >> 5, og = q & 3, kg = q >> 2;
  // ---- stage weights once: slot s -> k=s>>2, o4=s&3 (0,1 gate; 2,3 noise)
  #pragma unroll
  for (int i = 0; i < 16; ++i) {
    int s = t + (i << 8);
    int k = s >> 2, o4 = s & 3;
    const float* src = (o4 < 2) ? (wg + (size_t)k * NE + (o4 << 2))
                                : (wn + (size_t)k * NE + ((o4 - 2) << 2));
    stage16(src, smem + WL_OFF + s * 16);
  }
  // ---- x staging bases: slot s = i*256+t -> row s>>5, slot j=s&31, rotated
  const float* xsp0; const float* xsp1; const float* xsp2; const float* xsp3;
  int lds0, lds1, lds2, lds3;
  {
    int s0 = t, s1 = t + 256, s2 = t + 512, s3 = t + 768;
    int ts0 = s0 >> 5, ts1 = s1 >> 5, ts2 = s2 >> 5, ts3 = s3 >> 5;
    xsp0 = x + (size_t)(n0 + ts0) * DIM + ((( (s0 & 31) + ts0) & 31) << 2);
    xsp1 = x + (size_t)(n0 + ts1) * DIM + ((( (s1 & 31) + ts1) & 31) << 2);
    xsp2 = x + (size_t)(n0 + ts2) * DIM + ((( (s2 & 31) + ts2) & 31) << 2);
    xsp3 = x + (size_t)(n0 + ts3) * DIM + ((( (s3 & 31) + ts3) & 31) << 2);
    lds0 = s0 * 16; lds1 = s1 * 16; lds2 = s2 * 16; lds3 = s3 * 16;
  }
  #define STAGE_X(C) { \
    char* bb = smem + XB_OFF + (((C) & 3) << 14); \
    int ko = (C) << 7; \
    stage16(xsp0 + ko, bb + lds0); stage16(xsp1 + ko, bb + lds1); \
    stage16(xsp2 + ko, bb + lds2); stage16(xsp3 + ko, bb + lds3); }
  STAGE_X(0) STAGE_X(1) STAGE_X(2)
  WAITVM(8)       // w + chunk0 landed; chunks 1,2 in flight
  SBAR()
  float4 acc = Z4;
  const float* wb = wl + (og << 2);
  #pragma unroll
  for (int c = 0; c < 8; ++c) {
    const float* xb = (const float*)(smem + XB_OFF + ((c & 3) << 14)) + (tok << 7);
    #pragma unroll
    for (int k4 = 0; k4 < 16; ++k4) {
      int kk = (kg << 4) + k4;
      float4 xv = *(const float4*)(xb + (((kk - tok) & 31) << 2));
      int kgl = (c << 7) + (kk << 2);
      float4 w0 = *(const float4*)(wb + ((kgl + 0) << 4));
      float4 w1 = *(const float4*)(wb + ((kgl + 1) << 4));
      float4 w2 = *(const float4*)(wb + ((kgl + 2) << 4));
      float4 w3 = *(const float4*)(wb + ((kgl + 3) << 4));
      FMA4(acc, xv.x, w0); FMA4(acc, xv.y, w1);
      FMA4(acc, xv.z, w2); FMA4(acc, xv.w, w3);
    }
    if (c + 3 < 8) STAGE_X(c + 3)
    if (c < 5)      { WAITVM(8) SBAR() }
    else if (c == 5){ WAITVM(4) SBAR() }
    else if (c == 6){ WAITVM(0) SBAR() }
  }
  // ---- kg-reduce via pdf overlay (x buffers dead now except buf3; pdf=buf0)
  *(float4*)&pdf[((kg << 5) + tok) * 20 + (og << 2)] = acc;
  SBAR()
  #pragma unroll
  for (int i = 0; i < 2; ++i) {
    int idx = t + (i << 8);
    int ts = idx >> 4, o = idx & 15;
    lgS[ts * 20 + o] = pdf[ts * 20 + o] + pdf[(32 + ts) * 20 + o];
  }
  SBAR()
  if (t < 32) {
    int n = n0 + t;
    float cl[8], st[8], lg[8];
    float4 nzv0 = *(const float4*)(nz + (size_t)n * NE);
    float4 nzv1 = *(const float4*)(nz + (size_t)n * NE + 4);
    float nzv[8] = {nzv0.x, nzv0.y, nzv0.z, nzv0.w, nzv1.x, nzv1.y, nzv1.z, nzv1.w};
    #pragma unroll
    for (int e = 0; e < 8; ++e) cl[e] = lgS[t * 20 + e];
    #pragma unroll
    for (int e = 0; e < 8; ++e) {
      st[e] = softplusf(lgS[t * 20 + 8 + e]) + 0.01f;
      lg[e] = fmaf(nzv[e], st[e], cl[e]);
    }
    float m1 = -1e30f, m2 = -1e30f; int idx = 0;
    #pragma unroll
    for (int e = 0; e < 8; ++e) {
      float v = lg[e];
      if (v > m1)      { m2 = m1; m1 = v; idx = e; }
      else if (v > m2) { m2 = v; }
    }
    eid[n] = idx;
    float pr[8], cw[8];
    #pragma unroll
    for (int e = 0; e < 8; ++e) {
      float thr = (lg[e] > m2) ? m2 : m1;
      pr[e] = ncdf((cl[e] - thr) / st[e]);
    }
    #pragma unroll
    for (int e = 0; e < 8; ++e) cw[e] = (float)__popcll(__ballot(idx == e));
    #pragma unroll
    for (int e = 0; e < 8; ++e) {
      #pragma unroll
      for (int off = 1; off <= 16; off <<= 1) pr[e] += __shfl_xor(pr[e], off);
    }
    if (t == 0) {
      #pragma unroll
      for (int e = 0; e < 8; ++e) {
        part[blockIdx.x * 16 + e]     = cw[e];
        part[blockIdx.x * 16 + 8 + e] = pr[e];
      }
    }
  }
  #undef STAGE_X
}

// ---------------------------------------------------------------------------
// kC: fused counts reduction (256x16 partials) + bucket scatter. 32 blocks.
// ---------------------------------------------------------------------------
__global__ __launch_bounds__(256) void kC(const float* __restrict__ part,
    const int* __restrict__ eid, int* __restrict__ fill, int* __restrict__ bucket,
    float* __restrict__ outIL, int* __restrict__ counts) {
  __shared__ float red[16][16];
  __shared__ int cnt_s[8], lcnt[8], lbase[8];
  int t = threadIdx.x;
  int s = t & 15, g = t >> 4;
  float sum = 0.f;
  #pragma unroll
  for (int j = 0; j < 16; ++j) sum += part[(g + 16 * j) * 16 + s];
  red[g][s] = sum;
  if (t < 8) lcnt[t] = 0;
  __syncthreads();
  if (t < 16) {
    float tot = 0.f;
    #pragma unroll
    for (int gg = 0; gg < 16; ++gg) tot += red[gg][t];
    if (blockIdx.x == 0) outIL[t] = tot;
    if (t < 8) {
      cnt_s[t] = (int)(tot + 0.5f);
      if (blockIdx.x == 0) counts[t] = (int)(tot + 0.5f);
    }
  }
  __syncthreads();
  int n = blockIdx.x * 256 + t;
  int e = eid[n];
  int rank = atomicAdd(&lcnt[e], 1);
  __syncthreads();
  if (t < 8) lbase[t] = atomicAdd(&fill[t], lcnt[t]);
  __syncthreads();
  int off = 0;
  #pragma unroll
  for (int i = 0; i < 8; ++i) if (i < e) off += cnt_s[i];
  bucket[off + lbase[e] + rank] = n;
}

// ---------------------------------------------------------------------------
// kD4: h_sorted = lora_a[e] @ x[bucket], same pipelined structure as kA4.
// la[e][16][1024] staged once (64 KB); w-reads are scalar broadcasts.
// ---------------------------------------------------------------------------
__global__ __launch_bounds__(256) void kD4(const float* __restrict__ x,
    const float* __restrict__ la, const int* __restrict__ counts,
    const int* __restrict__ bucket, float* __restrict__ h) {
  extern __shared__ char smem[];
  float* lal = (float*)(smem + WL_OFF);
  float* pdf = (float*)(smem + XB_OFF);
  int* toks  = (int*)(smem + 131072);
  int tile = blockIdx.x;
  int e = -1, jt = 0, off = 0;
  { int tot = 0, o = 0;
    #pragma unroll
    for (int i = 0; i < 8; ++i) {
      int c = counts[i]; int nt = (c + 31) >> 5;
      if (e < 0 && tile < tot + nt) { e = i; jt = tile - tot; off = o; }
      tot += nt; o += c;
    } }
  if (e < 0) return;
  int cnt = counts[e];
  int p0 = off + (jt << 5);
  int valid = min(32, cnt - (jt << 5));
  int t = threadIdx.x;
  if (t < 32) toks[t] = bucket[p0 + min(t, valid - 1)];
  __syncthreads();                      // toks visible; vmcnt drained
  int tok = t & 31, q = t >> 5, og = q & 3, kg = q >> 2;
  // stage la[e] once (linear [16][1024])
  #pragma unroll
  for (int i = 0; i < 16; ++i) {
    int s = t + (i << 8);
    stage16(la + (size_t)e * (NR * DIM) + ((size_t)s << 2), smem + WL_OFF + s * 16);
  }
  const float* xsp0; const float* xsp1; const float* xsp2; const float* xsp3;
  int lds0, lds1, lds2, lds3;
  {
    int s0 = t, s1 = t + 256, s2 = t + 512, s3 = t + 768;
    int ts0 = s0 >> 5, ts1 = s1 >> 5, ts2 = s2 >> 5, ts3 = s3 >> 5;
    xsp0 = x + (size_t)toks[ts0] * DIM + ((((s0 & 31) + ts0) & 31) << 2);
    xsp1 = x + (size_t)toks[ts1] * DIM + ((((s1 & 31) + ts1) & 31) << 2);
    xsp2 = x + (size_t)toks[ts2] * DIM + ((((s2 & 31) + ts2) & 31) << 2);
    xsp3 = x + (size_t)toks[ts3] * DIM + ((((s3 & 31) + ts3) & 31) << 2);
    lds0 = s0 * 16; lds1 = s1 * 16; lds2 = s2 * 16; lds3 = s3 * 16;
  }
  #define STAGE_X(C) { \
    char* bb = smem + XB_OFF + (((C) & 3) << 14); \
    int ko = (C) << 7; \
    stage16(xsp0 + ko, bb + lds0); stage16(xsp1 + ko, bb + lds1); \
    stage16(xsp2 + ko, bb + lds2); stage16(xsp3 + ko, bb + lds3); }
  STAGE_X(0) STAGE_X(1) STAGE_X(2)
  WAITVM(8)
  SBAR()
  float4 acc = Z4;
  int og4k = (og << 2) * DIM;
  #pragma unroll
  for (int c = 0; c < 8; ++c) {
    const float* xb = (const float*)(smem + XB_OFF + ((c & 3) << 14)) + (tok << 7);
    #pragma unroll
    for (int k4 = 0; k4 < 16; ++k4) {
      int kk = (kg << 4) + k4;
      float4 xv = *(const float4*)(xb + (((kk - tok) & 31) << 2));
      int kgl = (c << 7) + (kk << 2);
      #define KSTEP(M, XS) { int k_ = kgl + (M); \
        acc.x = fmaf((XS), lal[og4k + k_], acc.x); \
        acc.y = fmaf((XS), lal[og4k + DIM + k_], acc.y); \
        acc.z = fmaf((XS), lal[og4k + 2 * DIM + k_], acc.z); \
        acc.w = fmaf((XS), lal[og4k + 3 * DIM + k_], acc.w); }
      KSTEP(0, xv.x) KSTEP(1, xv.y) KSTEP(2, xv.z) KSTEP(3, xv.w)
      #undef KSTEP
    }
    if (c + 3 < 8) STAGE_X(c + 3)
    if (c < 5)      { WAITVM(8) SBAR() }
    else if (c == 5){ WAITVM(4) SBAR() }
    else if (c == 6){ WAITVM(0) SBAR() }
  }
  *(float4*)&pdf[((kg << 5) + tok) * 20 + (og << 2)] = acc;
  SBAR()
  if (t < 128) {
    int ts = t >> 2, r4 = (t & 3) << 2;
    if (ts < valid) {
      float4 v;
      v.x = pdf[ts * 20 + r4 + 0] + pdf[(32 + ts) * 20 + r4 + 0];
      v.y = pdf[ts * 20 + r4 + 1] + pdf[(32 + ts) * 20 + r4 + 1];
      v.z = pdf[ts * 20 + r4 + 2] + pdf[(32 + ts) * 20 + r4 + 2];
      v.w = pdf[ts * 20 + r4 + 3] + pdf[(32 + ts) * 20 + r4 + 3];
      *(float4*)(h + (size_t)(p0 + ts) * NR + r4) = v;
    }
  }
  #undef STAGE_X
}

// ---------------------------------------------------------------------------
// kE: out[n] = lora_b[e] @ h_sorted. Tiles: 64 tokens x 256 outs. (unchanged)
// ---------------------------------------------------------------------------
__global__ __launch_bounds__(256) void kE(const float* __restrict__ h,
    const float* __restrict__ lb, const int* __restrict__ counts,
    const int* __restrict__ bucket, float* __restrict__ out) {
  __shared__ float bt[16][260];
  __shared__ float ht[16][64];
  __shared__ int toks[64];
  int tile = blockIdx.y;
  int e = -1, jt = 0, off = 0;
  { int tot = 0, o = 0;
    #pragma unroll
    for (int i = 0; i < 8; ++i) {
      int c = counts[i]; int nt = (c + 63) >> 6;
      if (e < 0 && tile < tot + nt) { e = i; jt = tile - tot; off = o; }
      tot += nt; o += c;
    } }
  if (e < 0) return;
  int cnt = counts[e];
  int p0 = off + (jt << 6);
  int valid = min(64, cnt - (jt << 6));
  int o0 = blockIdx.x << 8;
  int t = threadIdx.x;
  if (t < 64) toks[t] = bucket[p0 + min(t, valid - 1)];
  const float* bbase = lb + ((size_t)e * NO + o0) * NR;
  #pragma unroll
  for (int kk = 0; kk < 4; ++kk) {
    int idx = (kk << 8) + t;
    int o = idx >> 2, rq = (idx & 3) << 2;
    float4 v = *(const float4*)(bbase + o * NR + rq);
    bt[rq + 0][o] = v.x; bt[rq + 1][o] = v.y; bt[rq + 2][o] = v.z; bt[rq + 3][o] = v.w;
  }
  { int tok = t >> 2, rq = (t & 3) << 2;
    float4 v = *(const float4*)(h + (size_t)(p0 + min(tok, valid - 1)) * NR + rq);
    ht[rq + 0][tok] = v.x; ht[rq + 1][tok] = v.y; ht[rq + 2][tok] = v.z; ht[rq + 3][tok] = v.w; }
  __syncthreads();
  int og = t & 31, tokg = t >> 5;
  int ob = og << 2, tb = tokg << 3;
  float4 z = Z4;
  float4 aL0=z,aL1=z,aL2=z,aL3=z,aL4=z,aL5=z,aL6=z,aL7=z;
  float4 aH0=z,aH1=z,aH2=z,aH3=z,aH4=z,aH5=z,aH6=z,aH7=z;
  #pragma unroll
  for (int r = 0; r < 16; ++r) {
    float4 blo = *(const float4*)&bt[r][ob];
    float4 bhi = *(const float4*)&bt[r][ob + 128];
    float4 h0  = *(const float4*)&ht[r][tb];
    float4 h1  = *(const float4*)&ht[r][tb + 4];
    FMA4(aL0, h0.x, blo); FMA4(aH0, h0.x, bhi);
    FMA4(aL1, h0.y, blo); FMA4(aH1, h0.y, bhi);
    FMA4(aL2, h0.z, blo); FMA4(aH2, h0.z, bhi);
    FMA4(aL3, h0.w, blo); FMA4(aH3, h0.w, bhi);
    FMA4(aL4, h1.x, blo); FMA4(aH4, h1.x, bhi);
    FMA4(aL5, h1.y, blo); FMA4(aH5, h1.y, bhi);
    FMA4(aL6, h1.z, blo); FMA4(aH6, h1.z, bhi);
    FMA4(aL7, h1.w, blo); FMA4(aH7, h1.w, bhi);
  }
  #define ST(J, AL, AH) { int tt = tb + (J); if (tt < valid) { \
      float* p = out + (size_t)toks[tt] * NO + o0 + ob; \
      *(float4*)p = AL; *(float4*)(p + 128) = AH; } }
  ST(0, aL0, aH0); ST(1, aL1, aH1); ST(2, aL2, aH2); ST(3, aL3, aH3);
  ST(4, aL4, aH4); ST(5, aL5, aH5); ST(6, aL6, aH6); ST(7, aL7, aH7);
  #undef ST
}

// ---------------------------------------------------------------------------
extern "C" void kernel_launch(void* const* d_in, const int* in_sizes, int n_in,
                              void* d_out, int out_size, void* d_ws, size_t ws_size,
                              hipStream_t stream) {
  const float* x  = (const float*)d_in[0];
  const float* wg = (const float*)d_in[1];
  const float* wn = (const float*)d_in[2];
  const float* la = (const float*)d_in[3];
  const float* lb = (const float*)d_in[4];
  const float* nz = (const float*)d_in[5];
  float* out = (float*)d_out;

  char* ws = (char*)d_ws;
  float* h        = (float*)(ws);                 // 524288 B
  int*   eid      = (int*)  (ws + 524288);        // 32768 B
  int*   bucket   = (int*)  (ws + 557056);        // 32768 B
  float* partials = (float*)(ws + 589824);        // 16384 B (256*16*4)
  int*   counts   = (int*)  (ws + 606208);        // 32 B
  int*   fill     = (int*)  (ws + 606240);        // 32 B

  hipFuncSetAttribute((const void*)kA4, hipFuncAttributeMaxDynamicSharedMemorySize, KA4_SMEM);
  hipFuncSetAttribute((const void*)kD4, hipFuncAttributeMaxDynamicSharedMemorySize, KD4_SMEM);
  hipMemsetAsync(fill, 0, 32, stream);
  kA4<<<256, 256, KA4_SMEM, stream>>>(x, wg, wn, nz, eid, partials);
  kC<<<32, 256, 0, stream>>>(partials, eid, fill, bucket, out + OUT_ELEMS, counts);
  kD4<<<264, 256, KD4_SMEM, stream>>>(x, la, counts, bucket, h);
  kE<<<dim3(12, 135), 256, 0, stream>>>(h, lb, counts, bucket, out);
}

// Round 11
// 79.799 us; speedup vs baseline: 2.2706x; 2.2706x over previous
//
#include <hip/hip_runtime.h>
#include <math.h>

#define N_TOK 8192
#define DIM   1024
#define NE    8
#define NR    16
#define NO    3072
#define OUT_ELEMS (N_TOK * NO)   // 25165824

__device__ __forceinline__ float softplusf(float z) {
  return z > 0.f ? z + log1pf(expf(-z)) : log1pf(expf(z));
}
__device__ __forceinline__ float ncdf(float z) {
  return 0.5f * erfcf(-z * 0.70710678118654752f);
}

#define FMA4(A, S, W) { (A).x = fmaf((S),(W).x,(A).x); (A).y = fmaf((S),(W).y,(A).y); \
                        (A).z = fmaf((S),(W).z,(A).z); (A).w = fmaf((S),(W).w,(A).w); }
#define DOT4ACC(ACC, X, W) ACC = fmaf((X).x,(W).x, fmaf((X).y,(W).y, fmaf((X).z,(W).z, fmaf((X).w,(W).w,(ACC)))))
#define Z4 make_float4(0.f,0.f,0.f,0.f)

// ---------------------------------------------------------------------------
// kA8: gating GEMM, kE-style. 512 blocks x 16 tokens x 16 outs, K=1024 in
// 8 chunks of 128. Per chunk: reg-prefetch 4 float4/thread (x 8KB + W 8KB,
// coalesced) -> LDS (padded), 2 barriers, balanced FMA loop. ~25KB LDS ->
// whole grid co-resident (2 blocks/CU, capacity 6). acc stays in registers;
// one LDS reduce over the 4 k-quarter waves at the end.
// ---------------------------------------------------------------------------
__global__ __launch_bounds__(256) void kA8(const float* __restrict__ x,
    const float* __restrict__ wg, const float* __restrict__ wn,
    const float* __restrict__ nz, int* __restrict__ eid, float* __restrict__ part) {
  __shared__ float xl[16 * 132];        // x chunk [tok][128k], pad 132
  __shared__ float wl[128 * 20];        // W chunk [k][16 outs], pad 20
  __shared__ float accd[4 * 16 * 20];   // [kh][tok][16]
  __shared__ float lgS[16 * 20];
  int t = threadIdx.x;
  int n0 = blockIdx.x << 4;
  int tok = t & 15, og = (t >> 4) & 3, kh = t >> 6;
  // staging ids: x row tx cols jx*8..; W row kw half hw (0=gate,1=noise)
  int tx = t >> 4, jx = t & 15;
  int kw = t >> 1, hw = t & 1;
  const float* xsrc = x + (size_t)(n0 + tx) * DIM + (jx << 3);
  const float* wsrc = (hw == 0) ? (wg + (size_t)kw * NE) : (wn + (size_t)kw * NE);
  float4 xa0 = *(const float4*)(xsrc);
  float4 xa1 = *(const float4*)(xsrc + 4);
  float4 wa0 = *(const float4*)(wsrc);
  float4 wa1 = *(const float4*)(wsrc + 4);
  float4 acc = Z4;
  for (int c = 0; c < 8; ++c) {
    __syncthreads();
    *(float4*)&xl[tx * 132 + (jx << 3)]     = xa0;
    *(float4*)&xl[tx * 132 + (jx << 3) + 4] = xa1;
    *(float4*)&wl[kw * 20 + (hw << 3)]      = wa0;
    *(float4*)&wl[kw * 20 + (hw << 3) + 4]  = wa1;
    __syncthreads();
    if (c < 7) {
      int xo = (c + 1) << 7;
      xa0 = *(const float4*)(xsrc + xo);
      xa1 = *(const float4*)(xsrc + xo + 4);
      int wo = (c + 1) << 10;               // 128 rows * 8 floats
      wa0 = *(const float4*)(wsrc + wo);
      wa1 = *(const float4*)(wsrc + wo + 4);
    }
    const float* xr = &xl[tok * 132 + (kh << 5)];
    #pragma unroll
    for (int k4 = 0; k4 < 8; ++k4) {
      float4 xv = *(const float4*)(xr + (k4 << 2));
      const float* wb = &wl[((kh << 5) + (k4 << 2)) * 20 + (og << 2)];
      float4 w0 = *(const float4*)(wb + 0);
      float4 w1 = *(const float4*)(wb + 20);
      float4 w2 = *(const float4*)(wb + 40);
      float4 w3 = *(const float4*)(wb + 60);
      FMA4(acc, xv.x, w0); FMA4(acc, xv.y, w1);
      FMA4(acc, xv.z, w2); FMA4(acc, xv.w, w3);
    }
  }
  *(float4*)&accd[kh * 320 + tok * 20 + (og << 2)] = acc;
  __syncthreads();
  { int ts = t >> 4, o = t & 15;
    lgS[ts * 20 + o] = accd[ts * 20 + o] + accd[320 + ts * 20 + o]
                     + accd[640 + ts * 20 + o] + accd[960 + ts * 20 + o]; }
  __syncthreads();
  if (t < 16) {
    int n = n0 + t;
    float cl[8], st[8], lg[8];
    float4 nzv0 = *(const float4*)(nz + (size_t)n * NE);
    float4 nzv1 = *(const float4*)(nz + (size_t)n * NE + 4);
    float nzv[8] = {nzv0.x, nzv0.y, nzv0.z, nzv0.w, nzv1.x, nzv1.y, nzv1.z, nzv1.w};
    #pragma unroll
    for (int e = 0; e < 8; ++e) cl[e] = lgS[t * 20 + e];
    #pragma unroll
    for (int e = 0; e < 8; ++e) {
      st[e] = softplusf(lgS[t * 20 + 8 + e]) + 0.01f;
      lg[e] = fmaf(nzv[e], st[e], cl[e]);
    }
    float m1 = -1e30f, m2 = -1e30f; int idx = 0;
    #pragma unroll
    for (int e = 0; e < 8; ++e) {
      float v = lg[e];
      if (v > m1)      { m2 = m1; m1 = v; idx = e; }
      else if (v > m2) { m2 = v; }
    }
    eid[n] = idx;
    float pr[8], cw[8];
    #pragma unroll
    for (int e = 0; e < 8; ++e) {
      float thr = (lg[e] > m2) ? m2 : m1;
      pr[e] = ncdf((cl[e] - thr) / st[e]);
    }
    #pragma unroll
    for (int e = 0; e < 8; ++e) cw[e] = (float)__popcll(__ballot(idx == e));
    #pragma unroll
    for (int e = 0; e < 8; ++e) {
      #pragma unroll
      for (int off = 1; off <= 8; off <<= 1) pr[e] += __shfl_xor(pr[e], off);
    }
    if (t == 0) {
      #pragma unroll
      for (int e = 0; e < 8; ++e) {
        part[blockIdx.x * 16 + e]     = cw[e];
        part[blockIdx.x * 16 + 8 + e] = pr[e];
      }
    }
  }
}

// ---------------------------------------------------------------------------
// kC: fused counts reduction (512x16 partials) + bucket scatter. 32 blocks.
// Block 0 writes importance/load (d_out tail) and counts.
// ---------------------------------------------------------------------------
__global__ __launch_bounds__(256) void kC(const float* __restrict__ part,
    const int* __restrict__ eid, int* __restrict__ fill, int* __restrict__ bucket,
    float* __restrict__ outIL, int* __restrict__ counts) {
  __shared__ float red[16][16];
  __shared__ int cnt_s[8], lcnt[8], lbase[8];
  int t = threadIdx.x;
  int s = t & 15, g = t >> 4;
  float sum = 0.f;
  #pragma unroll
  for (int j = 0; j < 32; ++j) sum += part[(g + 16 * j) * 16 + s];
  red[g][s] = sum;
  if (t < 8) lcnt[t] = 0;
  __syncthreads();
  if (t < 16) {
    float tot = 0.f;
    #pragma unroll
    for (int gg = 0; gg < 16; ++gg) tot += red[gg][t];
    if (blockIdx.x == 0) outIL[t] = tot;
    if (t < 8) {
      cnt_s[t] = (int)(tot + 0.5f);
      if (blockIdx.x == 0) counts[t] = (int)(tot + 0.5f);
    }
  }
  __syncthreads();
  int n = blockIdx.x * 256 + t;
  int e = eid[n];
  int rank = atomicAdd(&lcnt[e], 1);
  __syncthreads();
  if (t < 8) lbase[t] = atomicAdd(&fill[t], lcnt[t]);
  __syncthreads();
  int off = 0;
  #pragma unroll
  for (int i = 0; i < 8; ++i) if (i < e) off += cnt_s[i];
  bucket[off + lbase[e] + rank] = n;
}

// ---------------------------------------------------------------------------
// kD8: h_sorted = lora_a[e] @ x[bucket], same kE-style skeleton as kA8.
// 16 sorted tokens/tile; la[e] chunk staged row-major [16r][128k] like x;
// compute thread=(tok,rg,kh) does 4 r-dot4s per k4. ~24KB LDS.
// ---------------------------------------------------------------------------
__global__ __launch_bounds__(256) void kD8(const float* __restrict__ x,
    const float* __restrict__ la, const int* __restrict__ counts,
    const int* __restrict__ bucket, float* __restrict__ h) {
  __shared__ float xl[16 * 132];
  __shared__ float wl[16 * 132];
  __shared__ float accd[4 * 16 * 20];
  __shared__ float hS[16 * 20];
  __shared__ int toks[16];
  int tile = blockIdx.x;
  int e = -1, jt = 0, off = 0;
  { int tot = 0, o = 0;
    #pragma unroll
    for (int i = 0; i < 8; ++i) {
      int c = counts[i]; int nt = (c + 15) >> 4;
      if (e < 0 && tile < tot + nt) { e = i; jt = tile - tot; off = o; }
      tot += nt; o += c;
    } }
  if (e < 0) return;
  int cnt = counts[e];
  int p0 = off + (jt << 4);
  int valid = min(16, cnt - (jt << 4));
  int t = threadIdx.x;
  if (t < 16) toks[t] = bucket[p0 + min(t, valid - 1)];
  __syncthreads();
  int tok = t & 15, rg = (t >> 4) & 3, kh = t >> 6;
  int tx = t >> 4, jx = t & 15;
  const float* xsrc = x + (size_t)toks[tx] * DIM + (jx << 3);
  const float* wsrc = la + (size_t)e * (NR * DIM) + (size_t)tx * DIM + (jx << 3);
  float4 xa0 = *(const float4*)(xsrc);
  float4 xa1 = *(const float4*)(xsrc + 4);
  float4 wa0 = *(const float4*)(wsrc);
  float4 wa1 = *(const float4*)(wsrc + 4);
  float4 acc = Z4;
  for (int c = 0; c < 8; ++c) {
    __syncthreads();
    *(float4*)&xl[tx * 132 + (jx << 3)]     = xa0;
    *(float4*)&xl[tx * 132 + (jx << 3) + 4] = xa1;
    *(float4*)&wl[tx * 132 + (jx << 3)]     = wa0;
    *(float4*)&wl[tx * 132 + (jx << 3) + 4] = wa1;
    __syncthreads();
    if (c < 7) {
      int ko = (c + 1) << 7;
      xa0 = *(const float4*)(xsrc + ko);
      xa1 = *(const float4*)(xsrc + ko + 4);
      wa0 = *(const float4*)(wsrc + ko);
      wa1 = *(const float4*)(wsrc + ko + 4);
    }
    const float* xr  = &xl[tok * 132 + (kh << 5)];
    const float* wr0 = &wl[((rg << 2) + 0) * 132 + (kh << 5)];
    const float* wr1 = &wl[((rg << 2) + 1) * 132 + (kh << 5)];
    const float* wr2 = &wl[((rg << 2) + 2) * 132 + (kh << 5)];
    const float* wr3 = &wl[((rg << 2) + 3) * 132 + (kh << 5)];
    #pragma unroll
    for (int k4 = 0; k4 < 8; ++k4) {
      float4 xv = *(const float4*)(xr  + (k4 << 2));
      float4 w0 = *(const float4*)(wr0 + (k4 << 2));
      float4 w1 = *(const float4*)(wr1 + (k4 << 2));
      float4 w2 = *(const float4*)(wr2 + (k4 << 2));
      float4 w3 = *(const float4*)(wr3 + (k4 << 2));
      DOT4ACC(acc.x, xv, w0); DOT4ACC(acc.y, xv, w1);
      DOT4ACC(acc.z, xv, w2); DOT4ACC(acc.w, xv, w3);
    }
  }
  *(float4*)&accd[kh * 320 + tok * 20 + (rg << 2)] = acc;
  __syncthreads();
  { int ts = t >> 4, rr = t & 15;
    hS[ts * 20 + rr] = accd[ts * 20 + rr] + accd[320 + ts * 20 + rr]
                     + accd[640 + ts * 20 + rr] + accd[960 + ts * 20 + rr]; }
  __syncthreads();
  if (t < 64) {
    int tk = t >> 2, rq = (t & 3) << 2;
    if (tk < valid) {
      float4 v = make_float4(hS[tk * 20 + rq + 0], hS[tk * 20 + rq + 1],
                             hS[tk * 20 + rq + 2], hS[tk * 20 + rq + 3]);
      *(float4*)(h + (size_t)(p0 + tk) * NR + rq) = v;
    }
  }
}

// ---------------------------------------------------------------------------
// kE: out[n] = lora_b[e] @ h_sorted. Tiles: 64 tokens x 256 outs. (unchanged)
// ---------------------------------------------------------------------------
__global__ __launch_bounds__(256) void kE(const float* __restrict__ h,
    const float* __restrict__ lb, const int* __restrict__ counts,
    const int* __restrict__ bucket, float* __restrict__ out) {
  __shared__ float bt[16][260];
  __shared__ float ht[16][64];
  __shared__ int toks[64];
  int tile = blockIdx.y;
  int e = -1, jt = 0, off = 0;
  { int tot = 0, o = 0;
    #pragma unroll
    for (int i = 0; i < 8; ++i) {
      int c = counts[i]; int nt = (c + 63) >> 6;
      if (e < 0 && tile < tot + nt) { e = i; jt = tile - tot; off = o; }
      tot += nt; o += c;
    } }
  if (e < 0) return;
  int cnt = counts[e];
  int p0 = off + (jt << 6);
  int valid = min(64, cnt - (jt << 6));
  int o0 = blockIdx.x << 8;
  int t = threadIdx.x;
  if (t < 64) toks[t] = bucket[p0 + min(t, valid - 1)];
  const float* bbase = lb + ((size_t)e * NO + o0) * NR;
  #pragma unroll
  for (int kk = 0; kk < 4; ++kk) {
    int idx = (kk << 8) + t;
    int o = idx >> 2, rq = (idx & 3) << 2;
    float4 v = *(const float4*)(bbase + o * NR + rq);
    bt[rq + 0][o] = v.x; bt[rq + 1][o] = v.y; bt[rq + 2][o] = v.z; bt[rq + 3][o] = v.w;
  }
  { int tok = t >> 2, rq = (t & 3) << 2;
    float4 v = *(const float4*)(h + (size_t)(p0 + min(tok, valid - 1)) * NR + rq);
    ht[rq + 0][tok] = v.x; ht[rq + 1][tok] = v.y; ht[rq + 2][tok] = v.z; ht[rq + 3][tok] = v.w; }
  __syncthreads();
  int og = t & 31, tokg = t >> 5;
  int ob = og << 2, tb = tokg << 3;
  float4 z = Z4;
  float4 aL0=z,aL1=z,aL2=z,aL3=z,aL4=z,aL5=z,aL6=z,aL7=z;
  float4 aH0=z,aH1=z,aH2=z,aH3=z,aH4=z,aH5=z,aH6=z,aH7=z;
  #pragma unroll
  for (int r = 0; r < 16; ++r) {
    float4 blo = *(const float4*)&bt[r][ob];
    float4 bhi = *(const float4*)&bt[r][ob + 128];
    float4 h0  = *(const float4*)&ht[r][tb];
    float4 h1  = *(const float4*)&ht[r][tb + 4];
    FMA4(aL0, h0.x, blo); FMA4(aH0, h0.x, bhi);
    FMA4(aL1, h0.y, blo); FMA4(aH1, h0.y, bhi);
    FMA4(aL2, h0.z, blo); FMA4(aH2, h0.z, bhi);
    FMA4(aL3, h0.w, blo); FMA4(aH3, h0.w, bhi);
    FMA4(aL4, h1.x, blo); FMA4(aH4, h1.x, bhi);
    FMA4(aL5, h1.y, blo); FMA4(aH5, h1.y, bhi);
    FMA4(aL6, h1.z, blo); FMA4(aH6, h1.z, bhi);
    FMA4(aL7, h1.w, blo); FMA4(aH7, h1.w, bhi);
  }
  #define ST(J, AL, AH) { int tt = tb + (J); if (tt < valid) { \
      float* p = out + (size_t)toks[tt] * NO + o0 + ob; \
      *(float4*)p = AL; *(float4*)(p + 128) = AH; } }
  ST(0, aL0, aH0); ST(1, aL1, aH1); ST(2, aL2, aH2); ST(3, aL3, aH3);
  ST(4, aL4, aH4); ST(5, aL5, aH5); ST(6, aL6, aH6); ST(7, aL7, aH7);
  #undef ST
}

// ---------------------------------------------------------------------------
extern "C" void kernel_launch(void* const* d_in, const int* in_sizes, int n_in,
                              void* d_out, int out_size, void* d_ws, size_t ws_size,
                              hipStream_t stream) {
  const float* x  = (const float*)d_in[0];
  const float* wg = (const float*)d_in[1];
  const float* wn = (const float*)d_in[2];
  const float* la = (const float*)d_in[3];
  const float* lb = (const float*)d_in[4];
  const float* nz = (const float*)d_in[5];
  float* out = (float*)d_out;

  char* ws = (char*)d_ws;
  float* h        = (float*)(ws);                 // 524288 B
  int*   eid      = (int*)  (ws + 524288);        // 32768 B
  int*   bucket   = (int*)  (ws + 557056);        // 32768 B
  float* partials = (float*)(ws + 589824);        // 32768 B (512*16*4)
  int*   counts   = (int*)  (ws + 622592);        // 32 B
  int*   fill     = (int*)  (ws + 622624);        // 32 B

  hipMemsetAsync(fill, 0, 32, stream);
  kA8<<<512, 256, 0, stream>>>(x, wg, wn, nz, eid, partials);
  kC<<<32, 256, 0, stream>>>(partials, eid, fill, bucket, out + OUT_ELEMS, counts);
  kD8<<<519, 256, 0, stream>>>(x, la, counts, bucket, h);
  kE<<<dim3(12, 135), 256, 0, stream>>>(h, lb, counts, bucket, out);
}

// Round 12
// 72.004 us; speedup vs baseline: 2.5164x; 1.1082x over previous
//
#include <hip/hip_runtime.h>
#include <math.h>

#define N_TOK 8192
#define DIM   1024
#define NE    8
#define NR    16
#define NO    3072
#define OUT_ELEMS (N_TOK * NO)   // 25165824

__device__ __forceinline__ float softplusf(float z) {
  return z > 0.f ? z + log1pf(expf(-z)) : log1pf(expf(z));
}
__device__ __forceinline__ float ncdf(float z) {
  return 0.5f * erfcf(-z * 0.70710678118654752f);
}

#define FMA4(A, S, W) { (A).x = fmaf((S),(W).x,(A).x); (A).y = fmaf((S),(W).y,(A).y); \
                        (A).z = fmaf((S),(W).z,(A).z); (A).w = fmaf((S),(W).w,(A).w); }
#define DOT4ACC(ACC, X, W) ACC = fmaf((X).x,(W).x, fmaf((X).y,(W).y, fmaf((X).z,(W).z, fmaf((X).w,(W).w,(ACC)))))
#define Z4 make_float4(0.f,0.f,0.f,0.f)

// ---------------------------------------------------------------------------
// kA9: gating GEMM. 512 blocks x 16 tokens x 16 outs, K=1024 in 8 chunks of
// 128. Register tile 4 tok x 4 outs per thread (thread = tokq(4) x og(4) x
// kh(16)): per k4 = 8 ds_read_b128 : 64 FMA (2.5x fewer LDS-inst than R11).
// Staging identical to R11 (coalesced reg->LDS, 2 barriers/chunk).
// Block 0 zeroes `fill` (replaces hipMemsetAsync).
// ---------------------------------------------------------------------------
__global__ __launch_bounds__(256) void kA9(const float* __restrict__ x,
    const float* __restrict__ wg, const float* __restrict__ wn,
    const float* __restrict__ nz, int* __restrict__ eid, float* __restrict__ part,
    int* __restrict__ fill) {
  __shared__ float xl[16 * 132];        // x chunk [tok][128k] pad 132
  __shared__ float wl[128 * 20];        // W chunk [k][16 outs] pad 20
  __shared__ float accd[16 * 16 * 20];  // [kh][tok][16] partials (20 KB)
  __shared__ float lgS[16 * 20];
  int t = threadIdx.x;
  int n0 = blockIdx.x << 4;
  if (blockIdx.x == 0 && t < 8) fill[t] = 0;
  int tokq = t & 3, og = (t >> 2) & 3, kh = t >> 4;
  int tx = t >> 4, jx = t & 15;
  int kw = t >> 1, hw = t & 1;
  const float* xsrc = x + (size_t)(n0 + tx) * DIM + (jx << 3);
  const float* wsrc = (hw == 0) ? (wg + (size_t)kw * NE) : (wn + (size_t)kw * NE);
  float4 xa0 = *(const float4*)(xsrc);
  float4 xa1 = *(const float4*)(xsrc + 4);
  float4 wa0 = *(const float4*)(wsrc);
  float4 wa1 = *(const float4*)(wsrc + 4);
  float4 acc0 = Z4, acc1 = Z4, acc2 = Z4, acc3 = Z4;   // toks tokq+0/4/8/12
  for (int c = 0; c < 8; ++c) {
    __syncthreads();
    *(float4*)&xl[tx * 132 + (jx << 3)]     = xa0;
    *(float4*)&xl[tx * 132 + (jx << 3) + 4] = xa1;
    *(float4*)&wl[kw * 20 + (hw << 3)]      = wa0;
    *(float4*)&wl[kw * 20 + (hw << 3) + 4]  = wa1;
    __syncthreads();
    if (c < 7) {
      int xo = (c + 1) << 7;
      xa0 = *(const float4*)(xsrc + xo);
      xa1 = *(const float4*)(xsrc + xo + 4);
      int wo = (c + 1) << 10;
      wa0 = *(const float4*)(wsrc + wo);
      wa1 = *(const float4*)(wsrc + wo + 4);
    }
    #pragma unroll
    for (int k4 = 0; k4 < 2; ++k4) {
      int kk = (kh << 3) + (k4 << 2);
      float4 xv0 = *(const float4*)&xl[(tokq +  0) * 132 + kk];
      float4 xv1 = *(const float4*)&xl[(tokq +  4) * 132 + kk];
      float4 xv2 = *(const float4*)&xl[(tokq +  8) * 132 + kk];
      float4 xv3 = *(const float4*)&xl[(tokq + 12) * 132 + kk];
      const float* wb = &wl[kk * 20 + (og << 2)];
      float4 w0 = *(const float4*)(wb + 0);
      float4 w1 = *(const float4*)(wb + 20);
      float4 w2 = *(const float4*)(wb + 40);
      float4 w3 = *(const float4*)(wb + 60);
      FMA4(acc0, xv0.x, w0); FMA4(acc0, xv0.y, w1); FMA4(acc0, xv0.z, w2); FMA4(acc0, xv0.w, w3);
      FMA4(acc1, xv1.x, w0); FMA4(acc1, xv1.y, w1); FMA4(acc1, xv1.z, w2); FMA4(acc1, xv1.w, w3);
      FMA4(acc2, xv2.x, w0); FMA4(acc2, xv2.y, w1); FMA4(acc2, xv2.z, w2); FMA4(acc2, xv2.w, w3);
      FMA4(acc3, xv3.x, w0); FMA4(acc3, xv3.y, w1); FMA4(acc3, xv3.z, w2); FMA4(acc3, xv3.w, w3);
    }
  }
  { int b = kh * 320 + (og << 2);
    *(float4*)&accd[b + (tokq +  0) * 20] = acc0;
    *(float4*)&accd[b + (tokq +  4) * 20] = acc1;
    *(float4*)&accd[b + (tokq +  8) * 20] = acc2;
    *(float4*)&accd[b + (tokq + 12) * 20] = acc3; }
  __syncthreads();
  { int ts = t >> 4, o = t & 15;
    float s = 0.f;
    #pragma unroll
    for (int k2 = 0; k2 < 16; ++k2) s += accd[k2 * 320 + ts * 20 + o];
    lgS[ts * 20 + o] = s; }
  __syncthreads();
  if (t < 16) {
    int n = n0 + t;
    float cl[8], st[8], lg[8];
    float4 nzv0 = *(const float4*)(nz + (size_t)n * NE);
    float4 nzv1 = *(const float4*)(nz + (size_t)n * NE + 4);
    float nzv[8] = {nzv0.x, nzv0.y, nzv0.z, nzv0.w, nzv1.x, nzv1.y, nzv1.z, nzv1.w};
    #pragma unroll
    for (int e = 0; e < 8; ++e) cl[e] = lgS[t * 20 + e];
    #pragma unroll
    for (int e = 0; e < 8; ++e) {
      st[e] = softplusf(lgS[t * 20 + 8 + e]) + 0.01f;
      lg[e] = fmaf(nzv[e], st[e], cl[e]);
    }
    float m1 = -1e30f, m2 = -1e30f; int idx = 0;
    #pragma unroll
    for (int e = 0; e < 8; ++e) {
      float v = lg[e];
      if (v > m1)      { m2 = m1; m1 = v; idx = e; }
      else if (v > m2) { m2 = v; }
    }
    eid[n] = idx;
    float pr[8], cw[8];
    #pragma unroll
    for (int e = 0; e < 8; ++e) {
      float thr = (lg[e] > m2) ? m2 : m1;
      pr[e] = ncdf((cl[e] - thr) / st[e]);
    }
    #pragma unroll
    for (int e = 0; e < 8; ++e) cw[e] = (float)__popcll(__ballot(idx == e));
    #pragma unroll
    for (int e = 0; e < 8; ++e) {
      #pragma unroll
      for (int off = 1; off <= 8; off <<= 1) pr[e] += __shfl_xor(pr[e], off);
    }
    if (t == 0) {
      #pragma unroll
      for (int e = 0; e < 8; ++e) {
        part[blockIdx.x * 16 + e]     = cw[e];
        part[blockIdx.x * 16 + 8 + e] = pr[e];
      }
    }
  }
}

// ---------------------------------------------------------------------------
// kC: fused counts reduction (512x16 partials) + bucket scatter. 32 blocks.
// ---------------------------------------------------------------------------
__global__ __launch_bounds__(256) void kC(const float* __restrict__ part,
    const int* __restrict__ eid, int* __restrict__ fill, int* __restrict__ bucket,
    float* __restrict__ outIL, int* __restrict__ counts) {
  __shared__ float red[16][16];
  __shared__ int cnt_s[8], lcnt[8], lbase[8];
  int t = threadIdx.x;
  int s = t & 15, g = t >> 4;
  float sum = 0.f;
  #pragma unroll
  for (int j = 0; j < 32; ++j) sum += part[(g + 16 * j) * 16 + s];
  red[g][s] = sum;
  if (t < 8) lcnt[t] = 0;
  __syncthreads();
  if (t < 16) {
    float tot = 0.f;
    #pragma unroll
    for (int gg = 0; gg < 16; ++gg) tot += red[gg][t];
    if (blockIdx.x == 0) outIL[t] = tot;
    if (t < 8) {
      cnt_s[t] = (int)(tot + 0.5f);
      if (blockIdx.x == 0) counts[t] = (int)(tot + 0.5f);
    }
  }
  __syncthreads();
  int n = blockIdx.x * 256 + t;
  int e = eid[n];
  int rank = atomicAdd(&lcnt[e], 1);
  __syncthreads();
  if (t < 8) lbase[t] = atomicAdd(&fill[t], lcnt[t]);
  __syncthreads();
  int off = 0;
  #pragma unroll
  for (int i = 0; i < 8; ++i) if (i < e) off += cnt_s[i];
  bucket[off + lbase[e] + rank] = n;
}

// ---------------------------------------------------------------------------
// kD9: h_sorted = lora_a[e] @ x[bucket]. Same skeleton/register tile as kA9:
// thread = tokq(4) x rg(4) x kh(16); 4 tok x 4 r acc; la rows staged
// row-major [16r][128k] (coalesced); DOT4 form.
// ---------------------------------------------------------------------------
__global__ __launch_bounds__(256) void kD9(const float* __restrict__ x,
    const float* __restrict__ la, const int* __restrict__ counts,
    const int* __restrict__ bucket, float* __restrict__ h) {
  __shared__ float xl[16 * 132];
  __shared__ float wl[16 * 132];
  __shared__ float accd[16 * 16 * 20];
  __shared__ float hS[16 * 20];
  __shared__ int toks[16];
  int tile = blockIdx.x;
  int e = -1, jt = 0, off = 0;
  { int tot = 0, o = 0;
    #pragma unroll
    for (int i = 0; i < 8; ++i) {
      int c = counts[i]; int nt = (c + 15) >> 4;
      if (e < 0 && tile < tot + nt) { e = i; jt = tile - tot; off = o; }
      tot += nt; o += c;
    } }
  if (e < 0) return;
  int cnt = counts[e];
  int p0 = off + (jt << 4);
  int valid = min(16, cnt - (jt << 4));
  int t = threadIdx.x;
  if (t < 16) toks[t] = bucket[p0 + min(t, valid - 1)];
  __syncthreads();
  int tokq = t & 3, rg = (t >> 2) & 3, kh = t >> 4;
  int tx = t >> 4, jx = t & 15;
  const float* xsrc = x + (size_t)toks[tx] * DIM + (jx << 3);
  const float* wsrc = la + (size_t)e * (NR * DIM) + (size_t)tx * DIM + (jx << 3);
  float4 xa0 = *(const float4*)(xsrc);
  float4 xa1 = *(const float4*)(xsrc + 4);
  float4 wa0 = *(const float4*)(wsrc);
  float4 wa1 = *(const float4*)(wsrc + 4);
  float4 acc0 = Z4, acc1 = Z4, acc2 = Z4, acc3 = Z4;
  for (int c = 0; c < 8; ++c) {
    __syncthreads();
    *(float4*)&xl[tx * 132 + (jx << 3)]     = xa0;
    *(float4*)&xl[tx * 132 + (jx << 3) + 4] = xa1;
    *(float4*)&wl[tx * 132 + (jx << 3)]     = wa0;
    *(float4*)&wl[tx * 132 + (jx << 3) + 4] = wa1;
    __syncthreads();
    if (c < 7) {
      int ko = (c + 1) << 7;
      xa0 = *(const float4*)(xsrc + ko);
      xa1 = *(const float4*)(xsrc + ko + 4);
      wa0 = *(const float4*)(wsrc + ko);
      wa1 = *(const float4*)(wsrc + ko + 4);
    }
    #pragma unroll
    for (int k4 = 0; k4 < 2; ++k4) {
      int kk = (kh << 3) + (k4 << 2);
      float4 xv0 = *(const float4*)&xl[(tokq +  0) * 132 + kk];
      float4 xv1 = *(const float4*)&xl[(tokq +  4) * 132 + kk];
      float4 xv2 = *(const float4*)&xl[(tokq +  8) * 132 + kk];
      float4 xv3 = *(const float4*)&xl[(tokq + 12) * 132 + kk];
      const float* wb = &wl[(rg << 2) * 132 + kk];
      float4 a0 = *(const float4*)(wb + 0);
      float4 a1 = *(const float4*)(wb + 132);
      float4 a2 = *(const float4*)(wb + 264);
      float4 a3 = *(const float4*)(wb + 396);
      DOT4ACC(acc0.x, xv0, a0); DOT4ACC(acc0.y, xv0, a1); DOT4ACC(acc0.z, xv0, a2); DOT4ACC(acc0.w, xv0, a3);
      DOT4ACC(acc1.x, xv1, a0); DOT4ACC(acc1.y, xv1, a1); DOT4ACC(acc1.z, xv1, a2); DOT4ACC(acc1.w, xv1, a3);
      DOT4ACC(acc2.x, xv2, a0); DOT4ACC(acc2.y, xv2, a1); DOT4ACC(acc2.z, xv2, a2); DOT4ACC(acc2.w, xv2, a3);
      DOT4ACC(acc3.x, xv3, a0); DOT4ACC(acc3.y, xv3, a1); DOT4ACC(acc3.z, xv3, a2); DOT4ACC(acc3.w, xv3, a3);
    }
  }
  { int b = kh * 320 + (rg << 2);
    *(float4*)&accd[b + (tokq +  0) * 20] = acc0;
    *(float4*)&accd[b + (tokq +  4) * 20] = acc1;
    *(float4*)&accd[b + (tokq +  8) * 20] = acc2;
    *(float4*)&accd[b + (tokq + 12) * 20] = acc3; }
  __syncthreads();
  { int ts = t >> 4, rr = t & 15;
    float s = 0.f;
    #pragma unroll
    for (int k2 = 0; k2 < 16; ++k2) s += accd[k2 * 320 + ts * 20 + rr];
    hS[ts * 20 + rr] = s; }
  __syncthreads();
  if (t < 64) {
    int tk = t >> 2, rq = (t & 3) << 2;
    if (tk < valid) {
      float4 v = make_float4(hS[tk * 20 + rq + 0], hS[tk * 20 + rq + 1],
                             hS[tk * 20 + rq + 2], hS[tk * 20 + rq + 3]);
      *(float4*)(h + (size_t)(p0 + tk) * NR + rq) = v;
    }
  }
}

// ---------------------------------------------------------------------------
// kE: out[n] = lora_b[e] @ h_sorted. Tiles: 64 tokens x 256 outs. (unchanged)
// ---------------------------------------------------------------------------
__global__ __launch_bounds__(256) void kE(const float* __restrict__ h,
    const float* __restrict__ lb, const int* __restrict__ counts,
    const int* __restrict__ bucket, float* __restrict__ out) {
  __shared__ float bt[16][260];
  __shared__ float ht[16][64];
  __shared__ int toks[64];
  int tile = blockIdx.y;
  int e = -1, jt = 0, off = 0;
  { int tot = 0, o = 0;
    #pragma unroll
    for (int i = 0; i < 8; ++i) {
      int c = counts[i]; int nt = (c + 63) >> 6;
      if (e < 0 && tile < tot + nt) { e = i; jt = tile - tot; off = o; }
      tot += nt; o += c;
    } }
  if (e < 0) return;
  int cnt = counts[e];
  int p0 = off + (jt << 6);
  int valid = min(64, cnt - (jt << 6));
  int o0 = blockIdx.x << 8;
  int t = threadIdx.x;
  if (t < 64) toks[t] = bucket[p0 + min(t, valid - 1)];
  const float* bbase = lb + ((size_t)e * NO + o0) * NR;
  #pragma unroll
  for (int kk = 0; kk < 4; ++kk) {
    int idx = (kk << 8) + t;
    int o = idx >> 2, rq = (idx & 3) << 2;
    float4 v = *(const float4*)(bbase + o * NR + rq);
    bt[rq + 0][o] = v.x; bt[rq + 1][o] = v.y; bt[rq + 2][o] = v.z; bt[rq + 3][o] = v.w;
  }
  { int tok = t >> 2, rq = (t & 3) << 2;
    float4 v = *(const float4*)(h + (size_t)(p0 + min(tok, valid - 1)) * NR + rq);
    ht[rq + 0][tok] = v.x; ht[rq + 1][tok] = v.y; ht[rq + 2][tok] = v.z; ht[rq + 3][tok] = v.w; }
  __syncthreads();
  int og = t & 31, tokg = t >> 5;
  int ob = og << 2, tb = tokg << 3;
  float4 z = Z4;
  float4 aL0=z,aL1=z,aL2=z,aL3=z,aL4=z,aL5=z,aL6=z,aL7=z;
  float4 aH0=z,aH1=z,aH2=z,aH3=z,aH4=z,aH5=z,aH6=z,aH7=z;
  #pragma unroll
  for (int r = 0; r < 16; ++r) {
    float4 blo = *(const float4*)&bt[r][ob];
    float4 bhi = *(const float4*)&bt[r][ob + 128];
    float4 h0  = *(const float4*)&ht[r][tb];
    float4 h1  = *(const float4*)&ht[r][tb + 4];
    FMA4(aL0, h0.x, blo); FMA4(aH0, h0.x, bhi);
    FMA4(aL1, h0.y, blo); FMA4(aH1, h0.y, bhi);
    FMA4(aL2, h0.z, blo); FMA4(aH2, h0.z, bhi);
    FMA4(aL3, h0.w, blo); FMA4(aH3, h0.w, bhi);
    FMA4(aL4, h1.x, blo); FMA4(aH4, h1.x, bhi);
    FMA4(aL5, h1.y, blo); FMA4(aH5, h1.y, bhi);
    FMA4(aL6, h1.z, blo); FMA4(aH6, h1.z, bhi);
    FMA4(aL7, h1.w, blo); FMA4(aH7, h1.w, bhi);
  }
  #define ST(J, AL, AH) { int tt = tb + (J); if (tt < valid) { \
      float* p = out + (size_t)toks[tt] * NO + o0 + ob; \
      *(float4*)p = AL; *(float4*)(p + 128) = AH; } }
  ST(0, aL0, aH0); ST(1, aL1, aH1); ST(2, aL2, aH2); ST(3, aL3, aH3);
  ST(4, aL4, aH4); ST(5, aL5, aH5); ST(6, aL6, aH6); ST(7, aL7, aH7);
  #undef ST
}

// ---------------------------------------------------------------------------
extern "C" void kernel_launch(void* const* d_in, const int* in_sizes, int n_in,
                              void* d_out, int out_size, void* d_ws, size_t ws_size,
                              hipStream_t stream) {
  const float* x  = (const float*)d_in[0];
  const float* wg = (const float*)d_in[1];
  const float* wn = (const float*)d_in[2];
  const float* la = (const float*)d_in[3];
  const float* lb = (const float*)d_in[4];
  const float* nz = (const float*)d_in[5];
  float* out = (float*)d_out;

  char* ws = (char*)d_ws;
  float* h        = (float*)(ws);                 // 524288 B
  int*   eid      = (int*)  (ws + 524288);        // 32768 B
  int*   bucket   = (int*)  (ws + 557056);        // 32768 B
  float* partials = (float*)(ws + 589824);        // 32768 B (512*16*4)
  int*   counts   = (int*)  (ws + 622592);        // 32 B
  int*   fill     = (int*)  (ws + 622624);        // 32 B

  kA9<<<512, 256, 0, stream>>>(x, wg, wn, nz, eid, partials, fill);
  kC<<<32, 256, 0, stream>>>(partials, eid, fill, bucket, out + OUT_ELEMS, counts);
  kD9<<<519, 256, 0, stream>>>(x, la, counts, bucket, h);
  kE<<<dim3(12, 135), 256, 0, stream>>>(h, lb, counts, bucket, out);
}